// Round 20
// baseline (59.077 us; speedup 1.0000x reference)
//
#include <hip/hip_runtime.h>
#include <hip/hip_bf16.h>

typedef __bf16 bf16x8 __attribute__((ext_vector_type(8)));
typedef __bf16 bf16x4 __attribute__((ext_vector_type(4)));
typedef __bf16 bf16x2 __attribute__((ext_vector_type(2)));
typedef short i16x4 __attribute__((ext_vector_type(4)));
typedef float f32x4 __attribute__((ext_vector_type(4)));
typedef float f32x16 __attribute__((ext_vector_type(16)));

#define S_LEN 2048
#define D_DIM 64
#define NQT   32

// K=8 PV path: v_mfma_f32_32x32x8_bf16's A-frag (k = 4*(lane>>5)+i per 8-k
// step) matches the QK^T C-layout crow=(r&3)+8*(r>>2)+4h EXACTLY -> P feeds
// PV with ZERO cross-lane ops (deletes 8 ds_bpermute + 16 selects/tile-iter).
#if defined(__has_builtin)
#if __has_builtin(__builtin_amdgcn_mfma_f32_32x32x8bf16_1k)
#define HAVE_MFMA_X8 1
#else
#define HAVE_MFMA_X8 0
#endif
#else
#define HAVE_MFMA_X8 0
#endif

// pack two f32 -> u32 of 2 bf16 (compiler fuses to v_cvt_pk_bf16_f32)
static __device__ __forceinline__ unsigned pk2(float a, float b) {
  bf16x2 t; t[0] = (__bf16)a; t[1] = (__bf16)b;
  return __builtin_bit_cast(unsigned, t);
}

// ---------------- preprocess: 32x32-MFMA fragment images ----------------
__global__ __launch_bounds__(256) void preprocess_kernel(
    const float* __restrict__ Kg, const float* __restrict__ Vg,
    unsigned char* __restrict__ Kb, unsigned char* __restrict__ Vt) {
  __shared__ float buf[2048];   // 8 KB: one 32x64 fp32 tile
  const int tid  = threadIdx.x;
  const int tile = blockIdx.x;          // bh*64 + kt
  const float* kg = Kg + (long)tile * 2048;
  const float* vg = Vg + (long)tile * 2048;
  unsigned char* kb = Kb + (long)tile * 4096;
  unsigned char* vt = Vt + (long)tile * 4096;

  const int l = tid & 63, f = tid >> 6, h = l >> 5;

  {
    const float* kr = kg + (l & 31) * 64 + f * 16 + h * 8;
    float4 a = *reinterpret_cast<const float4*>(kr);
    float4 b = *reinterpret_cast<const float4*>(kr + 4);
    bf16x8 t;
    t[0]=(__bf16)a.x; t[1]=(__bf16)a.y; t[2]=(__bf16)a.z; t[3]=(__bf16)a.w;
    t[4]=(__bf16)b.x; t[5]=(__bf16)b.y; t[6]=(__bf16)b.z; t[7]=(__bf16)b.w;
    *reinterpret_cast<bf16x8*>(kb + tid * 16) = t;
  }
  #pragma unroll
  for (int i = 0; i < 2; ++i) {
    int idx = tid + 256 * i;
    *reinterpret_cast<float4*>(buf + idx * 4) =
        *reinterpret_cast<const float4*>(vg + idx * 4);
  }
  __syncthreads();
  {
    int dt = f >> 1, sp = f & 1;
    int d  = dt * 32 + (l & 31);
    bf16x8 t;
#if HAVE_MFMA_X8
    // chunk = [k-step s=2sp (8B) | k-step s=2sp+1 (8B)]; within step: k=4h+j
    #pragma unroll
    for (int j = 0; j < 4; ++j) t[j]     = (__bf16)buf[(sp*16 +     h*4 + j) * 64 + d];
    #pragma unroll
    for (int j = 0; j < 4; ++j) t[4 + j] = (__bf16)buf[(sp*16 + 8 + h*4 + j) * 64 + d];
#else
    int k0 = sp * 16 + h * 8;
    #pragma unroll
    for (int j = 0; j < 8; ++j) t[j] = (__bf16)buf[(k0 + j) * 64 + d];
#endif
    *reinterpret_cast<bf16x8*>(vt + tid * 16) = t;
  }
}

// ---------------- main: 64 q-rows per wave, balanced pairs, split-K x4 ----------------
// r14/r19 structure (verified best): block = 256 threads = 4 waves on pair
// (pi, 31-pi), two phases, 66 tile-iters/block (perfect balance, 2 blocks/CU).
// Sub-blocks A/B share every K/V fragment load. Wave w takes kt = w (mod 4);
// 4-way LDS flash-merge per sub-block. PV via K=8 MFMAs: P is lane-local.
__global__ __launch_bounds__(256, 2) void attn_fwd_q64(
    const float* __restrict__ Qg, const unsigned char* __restrict__ Kb,
    const unsigned char* __restrict__ Vt, float* __restrict__ Og) {
  __shared__ float o_sm[4][32][68];   // 34816 B merge arena (reused A then B)
  __shared__ float m_sm[4][32];
  __shared__ float l_sm[4][32];

  const int tid  = threadIdx.x;
  const int lane = tid & 63;
  const int w    = tid >> 6;     // wave 0..3 (k-residue)
  const int qc   = lane & 31;
  const int h    = lane >> 5;

  // decode: XCD-clustered bh (4 bh per XCD); pair index pi (0..15)
  const int b  = blockIdx.x;            // 0..511
  const int e  = b & 7;
  const int s  = b >> 3;                // 0..63
  const int bh = e + 8 * (s >> 4);      // 4 bh per XCD
  const int pi = s & 15;
  const long base = (long)bh * (S_LEN * D_DIM);

  const unsigned char* kb_bh = Kb + (long)bh * 64 * 4096 + lane * 16;
  const unsigned char* vt_bh = Vt + (long)bh * 64 * 4096 + lane * 16;

  bf16x8 kfr[4], vfr[4];
  auto ldK = [&](int kt) {
    const unsigned char* p = kb_bh + (long)kt * 4096;
    #pragma unroll
    for (int t = 0; t < 4; ++t)
      kfr[t] = *reinterpret_cast<const bf16x8*>(p + t * 1024);
  };
  auto ldV = [&](int kt) {
    const unsigned char* p = vt_bh + (long)kt * 4096;
    #pragma unroll
    for (int t = 0; t < 4; ++t)
      vfr[t] = *reinterpret_cast<const bf16x8*>(p + t * 1024);
  };

  // softmax + PV for one q-sub-block
  auto process = [&](f32x16& sa, float& m_run, float& l_run,
                     f32x16& po0, f32x16& po1) {
    float rmax;
    {
      float a0 = fmaxf(fmaxf(sa[0], sa[1]),  fmaxf(sa[2], sa[3]));
      float a1 = fmaxf(fmaxf(sa[4], sa[5]),  fmaxf(sa[6], sa[7]));
      float a2 = fmaxf(fmaxf(sa[8], sa[9]),  fmaxf(sa[10], sa[11]));
      float a3 = fmaxf(fmaxf(sa[12], sa[13]), fmaxf(sa[14], sa[15]));
      rmax = fmaxf(fmaxf(a0, a1), fmaxf(a2, a3));
      rmax = fmaxf(rmax, __shfl_xor(rmax, 32));
    }
    if (__any(rmax > m_run + 8.0f)) {       // defer-max (T13)
      float mn    = fmaxf(m_run, rmax);
      float alpha = exp2f(m_run - mn);
      m_run = mn;
      l_run *= alpha;
      #pragma unroll
      for (int r = 0; r < 16; ++r) {
        float ar = __shfl(alpha, (r & 3) + 8 * (r >> 2) + 4 * h);
        po0[r] *= ar;
        po1[r] *= ar;
      }
    }
    #pragma unroll
    for (int r = 0; r < 16; ++r) sa[r] = exp2f(sa[r] - m_run);
    {
      float s0 = (sa[0] + sa[1]) + (sa[2] + sa[3]);
      float s1 = (sa[4] + sa[5]) + (sa[6] + sa[7]);
      float s2 = (sa[8] + sa[9]) + (sa[10] + sa[11]);
      float s3 = (sa[12] + sa[13]) + (sa[14] + sa[15]);
      float rs = (s0 + s1) + (s2 + s3);
      l_run += rs + __shfl_xor(rs, 32);
    }
#if HAVE_MFMA_X8
    // P -> x8 A-frags: pa[s] = {sa[4s..4s+3]} (lane-local, zero shuffles)
    i16x4 pa[4];
    {
      union { unsigned u[2]; i16x4 q; } c;
      #pragma unroll
      for (int s4 = 0; s4 < 4; ++s4) {
        c.u[0] = pk2(sa[4*s4 + 0], sa[4*s4 + 1]);
        c.u[1] = pk2(sa[4*s4 + 2], sa[4*s4 + 3]);
        pa[s4] = c.q;
      }
    }
    union U8 { bf16x8 v; i16x4 q[2]; } v0, v1, v2, v3;
    v0.v = vfr[0]; v1.v = vfr[1]; v2.v = vfr[2]; v3.v = vfr[3];
    __builtin_amdgcn_s_setprio(1);
    po0 = __builtin_amdgcn_mfma_f32_32x32x8bf16_1k(pa[0], v0.q[0], po0, 0, 0, 0);
    po0 = __builtin_amdgcn_mfma_f32_32x32x8bf16_1k(pa[1], v0.q[1], po0, 0, 0, 0);
    po0 = __builtin_amdgcn_mfma_f32_32x32x8bf16_1k(pa[2], v1.q[0], po0, 0, 0, 0);
    po0 = __builtin_amdgcn_mfma_f32_32x32x8bf16_1k(pa[3], v1.q[1], po0, 0, 0, 0);
    po1 = __builtin_amdgcn_mfma_f32_32x32x8bf16_1k(pa[0], v2.q[0], po1, 0, 0, 0);
    po1 = __builtin_amdgcn_mfma_f32_32x32x8bf16_1k(pa[1], v2.q[1], po1, 0, 0, 0);
    po1 = __builtin_amdgcn_mfma_f32_32x32x8bf16_1k(pa[2], v3.q[0], po1, 0, 0, 0);
    po1 = __builtin_amdgcn_mfma_f32_32x32x8bf16_1k(pa[3], v3.q[1], po1, 0, 0, 0);
    __builtin_amdgcn_s_setprio(0);
#else
    bf16x8 pa0, pa1;
    {
      unsigned k0 = pk2(sa[0], sa[1]),   k1 = pk2(sa[2], sa[3]);
      unsigned k2 = pk2(sa[4], sa[5]),   k3 = pk2(sa[6], sa[7]);
      unsigned k4 = pk2(sa[8], sa[9]),   k5 = pk2(sa[10], sa[11]);
      unsigned k6 = pk2(sa[12], sa[13]), k7 = pk2(sa[14], sa[15]);
      unsigned x02 = h ? k0 : k2, x13 = h ? k1 : k3;
      unsigned x46 = h ? k4 : k6, x57 = h ? k5 : k7;
      unsigned p02 = (unsigned)__shfl_xor((int)x02, 32);
      unsigned p13 = (unsigned)__shfl_xor((int)x13, 32);
      unsigned p46 = (unsigned)__shfl_xor((int)x46, 32);
      unsigned p57 = (unsigned)__shfl_xor((int)x57, 32);
      union { unsigned u[4]; bf16x8 v; } a2, b2;
      a2.u[0] = h ? p02 : k0;  a2.u[1] = h ? p13 : k1;
      a2.u[2] = h ? k2 : p02;  a2.u[3] = h ? k3 : p13;
      b2.u[0] = h ? p46 : k4;  b2.u[1] = h ? p57 : k5;
      b2.u[2] = h ? k6 : p46;  b2.u[3] = h ? k7 : p57;
      pa0 = a2.v;
      pa1 = b2.v;
    }
    __builtin_amdgcn_s_setprio(1);
    po0 = __builtin_amdgcn_mfma_f32_32x32x16_bf16(pa0, vfr[0], po0, 0, 0, 0);
    po0 = __builtin_amdgcn_mfma_f32_32x32x16_bf16(pa1, vfr[1], po0, 0, 0, 0);
    po1 = __builtin_amdgcn_mfma_f32_32x32x16_bf16(pa0, vfr[2], po1, 0, 0, 0);
    po1 = __builtin_amdgcn_mfma_f32_32x32x16_bf16(pa1, vfr[3], po1, 0, 0, 0);
    __builtin_amdgcn_s_setprio(0);
#endif
  };

  // merge one 32-row sub-block: write partials -> sync -> 4-way flash-merge
  auto submerge = [&](const f32x16& po0, const f32x16& po1,
                      float m_run, float l_run, int qbase) {
    #pragma unroll
    for (int r = 0; r < 16; ++r) {
      int crow = (r & 3) + 8 * (r >> 2) + 4 * h;
      o_sm[w][crow][qc]      = po0[r];
      o_sm[w][crow][qc + 32] = po1[r];
    }
    if (h == 0) { m_sm[w][qc] = m_run; l_sm[w][qc] = l_run; }
    __syncthreads();
    {
      const int q  = tid >> 3;          // 0..31
      const int d0 = (tid & 7) * 8;     // 0,8,..56
      float m0 = m_sm[0][q], m1 = m_sm[1][q];
      float m2 = m_sm[2][q], m3 = m_sm[3][q];
      float M  = fmaxf(fmaxf(m0, m1), fmaxf(m2, m3));
      float a0 = exp2f(m0 - M), a1 = exp2f(m1 - M);
      float a2 = exp2f(m2 - M), a3 = exp2f(m3 - M);
      float inv = 1.0f / (a0 * l_sm[0][q] + a1 * l_sm[1][q]
                        + a2 * l_sm[2][q] + a3 * l_sm[3][q]);
      float* og = Og + base + (long)(qbase + q) * D_DIM + d0;
      #pragma unroll
      for (int half = 0; half < 2; ++half) {
        float4 x0 = *reinterpret_cast<const float4*>(&o_sm[0][q][d0 + 4 * half]);
        float4 x1 = *reinterpret_cast<const float4*>(&o_sm[1][q][d0 + 4 * half]);
        float4 x2 = *reinterpret_cast<const float4*>(&o_sm[2][q][d0 + 4 * half]);
        float4 x3 = *reinterpret_cast<const float4*>(&o_sm[3][q][d0 + 4 * half]);
        float4 o;
        o.x = (a0 * x0.x + a1 * x1.x + a2 * x2.x + a3 * x3.x) * inv;
        o.y = (a0 * x0.y + a1 * x1.y + a2 * x2.y + a3 * x3.y) * inv;
        o.z = (a0 * x0.z + a1 * x1.z + a2 * x2.z + a3 * x3.z) * inv;
        o.w = (a0 * x0.w + a1 * x1.w + a2 * x2.w + a3 * x3.w) * inv;
        *reinterpret_cast<float4*>(og + 4 * half) = o;
      }
    }
  };

  for (int phase = 0; phase < 2; ++phase) {
    const int g  = phase ? pi : (31 - pi);   // 64-row group
    const int q0 = g * 64;
    const int NT = 2 * g + 2;                // 32-wide k-tiles

    // Q fragments for sub-blocks A and B, prescaled by 1/8 * log2(e)
    bf16x8 qfA[4], qfB[4];
    {
      const float qsc = 0.125f * 1.44269504f;
      const float* qpA = Qg + base + (long)(q0 + qc) * D_DIM + h * 8;
      const float* qpB = qpA + 32 * D_DIM;
      #pragma unroll
      for (int t = 0; t < 4; ++t) {
        float4 f0 = *reinterpret_cast<const float4*>(qpA + t * 16);
        float4 f1 = *reinterpret_cast<const float4*>(qpA + t * 16 + 4);
        bf16x8 q;
        q[0]=(__bf16)(f0.x*qsc); q[1]=(__bf16)(f0.y*qsc);
        q[2]=(__bf16)(f0.z*qsc); q[3]=(__bf16)(f0.w*qsc);
        q[4]=(__bf16)(f1.x*qsc); q[5]=(__bf16)(f1.y*qsc);
        q[6]=(__bf16)(f1.z*qsc); q[7]=(__bf16)(f1.w*qsc);
        qfA[t] = q;
        f0 = *reinterpret_cast<const float4*>(qpB + t * 16);
        f1 = *reinterpret_cast<const float4*>(qpB + t * 16 + 4);
        q[0]=(__bf16)(f0.x*qsc); q[1]=(__bf16)(f0.y*qsc);
        q[2]=(__bf16)(f0.z*qsc); q[3]=(__bf16)(f0.w*qsc);
        q[4]=(__bf16)(f1.x*qsc); q[5]=(__bf16)(f1.y*qsc);
        q[6]=(__bf16)(f1.z*qsc); q[7]=(__bf16)(f1.w*qsc);
        qfB[t] = q;
      }
    }

    f32x16 poA0, poA1, poB0, poB1;
    #pragma unroll
    for (int r = 0; r < 16; ++r) { poA0[r]=0.f; poA1[r]=0.f; poB0[r]=0.f; poB1[r]=0.f; }
    float mA = -1e30f, lA = 0.f, mB = -1e30f, lB = 0.f;

    ldK(w);   // kt = w always exists in the 64-tile bh buffer
    ldV(w);

    for (int kt = w; kt < NT; kt += 4) {
      const bool more = (kt + 4 < NT);
      const bool doA  = (kt != NT - 1);   // tile NT-1 is fully past A's rows

      // S^T via mfma(K, Q) for both sub-blocks (shared kfr)
      f32x16 saA, saB;
      __builtin_amdgcn_s_setprio(1);
      if (doA) {
        #pragma unroll
        for (int r = 0; r < 16; ++r) saA[r] = 0.f;
        #pragma unroll
        for (int t = 0; t < 4; ++t)
          saA = __builtin_amdgcn_mfma_f32_32x32x16_bf16(kfr[t], qfA[t], saA, 0, 0, 0);
      }
      #pragma unroll
      for (int r = 0; r < 16; ++r) saB[r] = 0.f;
      #pragma unroll
      for (int t = 0; t < 4; ++t)
        saB = __builtin_amdgcn_mfma_f32_32x32x16_bf16(kfr[t], qfB[t], saB, 0, 0, 0);
      __builtin_amdgcn_s_setprio(0);

      if (more) ldK(kt + 4);   // prefetch next K (kfr free after both QKs)

      // causal diag masks: A at kt==NT-2, B at kt==NT-1; both reduce to crow>qc
      if (kt == NT - 2) {
        #pragma unroll
        for (int r = 0; r < 16; ++r)
          if (((r & 3) + 8 * (r >> 2) + 4 * h) > qc) saA[r] = -1e30f;
      }
      if (kt == NT - 1) {
        #pragma unroll
        for (int r = 0; r < 16; ++r)
          if (((r & 3) + 8 * (r >> 2) + 4 * h) > qc) saB[r] = -1e30f;
      }

      if (doA) process(saA, mA, lA, poA0, poA1);
      process(saB, mB, lB, poB0, poB1);

      if (more) ldV(kt + 4);   // prefetch next V
    }

    if (phase) __syncthreads();          // prior merge readers done
    submerge(poA0, poA1, mA, lA, q0);
    __syncthreads();                     // merge-A reads done before B writes
    submerge(poB0, poB1, mB, lB, q0 + 32);
  }
}

// ---------------- fallback (round-5 kernel) if ws too small ----------------
__global__ __launch_bounds__(256) void attn_fwd_fallback(
    const float* __restrict__ Vg, const float* __restrict__ Qg,
    const float* __restrict__ Kg, float* __restrict__ Og) {
  __shared__ __align__(16) unsigned char k_lds[64 * 128];
  __shared__ __align__(16) unsigned char vt_lds[64 * 128];
  __shared__ __align__(16) unsigned char p_lds[4][16 * 128];

  const int tid  = threadIdx.x;
  const int lane = tid & 63;
  const int w    = tid >> 6;
  const int lr   = lane & 15;
  const int lg   = lane >> 4;
  const int swz  = (lr & 7) << 4;

  const int lb = blockIdx.x;
  const int e  = lb & 7;
  const int s  = lb >> 3;
  const int bh = e + 8 * (s >> 5);
  const int qs = s & 31;
  const int qt = (qs & 1) ? (NQT - 1 - (qs >> 1)) : (qs >> 1);
  const long base = (long)bh * (S_LEN * D_DIM);
  const int q0 = qt * 64;

  bf16x8 qf[2];
  {
    const float qsc = 0.125f * 1.44269504f;
    const float* qp = Qg + base + (q0 + w * 16 + lr) * D_DIM + lg * 8;
    #pragma unroll
    for (int c = 0; c < 2; ++c) {
      float4 f0 = *reinterpret_cast<const float4*>(qp + c * 32);
      float4 f1 = *reinterpret_cast<const float4*>(qp + c * 32 + 4);
      bf16x8 t;
      t[0]=(__bf16)(f0.x*qsc); t[1]=(__bf16)(f0.y*qsc);
      t[2]=(__bf16)(f0.z*qsc); t[3]=(__bf16)(f0.w*qsc);
      t[4]=(__bf16)(f1.x*qsc); t[5]=(__bf16)(f1.y*qsc);
      t[6]=(__bf16)(f1.z*qsc); t[7]=(__bf16)(f1.w*qsc);
      qf[c] = t;
    }
  }
  bf16x8 onesf;
  #pragma unroll
  for (int j = 0; j < 8; ++j) onesf[j] = (lr == 0) ? (__bf16)1.0f : (__bf16)0.0f;

  f32x4 po[4], pl;
  float m_run = -1e30f;
  #pragma unroll
  for (int j = 0; j < 4; ++j) po[j] = (f32x4){0.f,0.f,0.f,0.f};
  pl = (f32x4){0.f,0.f,0.f,0.f};

  float4 kreg[4];
  float  vreg[16];
  const int d_ = lane;
  const int kb = w;

  auto load_regs = [&](int kt) {
    const float* kg = Kg + base + kt * (64 * D_DIM);
    #pragma unroll
    for (int i = 0; i < 4; ++i) {
      int idx = tid + 256 * i;
      int r = idx >> 4, f4 = idx & 15;
      kreg[i] = *reinterpret_cast<const float4*>(kg + r * 64 + f4 * 4);
    }
    const float* vg = Vg + base + kt * (64 * D_DIM);
    #pragma unroll
    for (int j = 0; j < 8; ++j) {
      vreg[j]     = vg[(kb * 8 + j) * 64 + d_];
      vreg[8 + j] = vg[((kb + 4) * 8 + j) * 64 + d_];
    }
  };
  auto write_buf = [&]() {
    #pragma unroll
    for (int i = 0; i < 4; ++i) {
      int idx = tid + 256 * i;
      int r = idx >> 4, f4 = idx & 15;
      bf16x4 t;
      t[0]=(__bf16)kreg[i].x; t[1]=(__bf16)kreg[i].y;
      t[2]=(__bf16)kreg[i].z; t[3]=(__bf16)kreg[i].w;
      int b = r * 128 + ((f4 * 8) ^ ((r & 7) << 4));
      *reinterpret_cast<bf16x4*>(&k_lds[b]) = t;
    }
    bf16x8 t0, t1;
    #pragma unroll
    for (int j = 0; j < 8; ++j) { t0[j] = (__bf16)vreg[j]; t1[j] = (__bf16)vreg[8+j]; }
    int b0 = d_ * 128 + ((kb * 16) ^ ((d_ & 7) << 4));
    int b1 = d_ * 128 + (((kb + 4) * 16) ^ ((d_ & 7) << 4));
    *reinterpret_cast<bf16x8*>(&vt_lds[b0]) = t0;
    *reinterpret_cast<bf16x8*>(&vt_lds[b1]) = t1;
  };

  load_regs(0);
  write_buf();
  __syncthreads();

  for (int kt = 0; kt <= qt; ++kt) {
    const bool last = (kt == qt);
    if (!last) load_regs(kt + 1);

    f32x4 sa[4];
    #pragma unroll
    for (int ct = 0; ct < 4; ++ct) sa[ct] = (f32x4){0.f,0.f,0.f,0.f};
    #pragma unroll
    for (int ct = 0; ct < 4; ++ct) {
      #pragma unroll
      for (int c = 0; c < 2; ++c) {
        int b = (ct * 16 + lr) * 128 + ((lg * 16 + c * 64) ^ swz);
        bf16x8 kf = *reinterpret_cast<const bf16x8*>(&k_lds[b]);
        sa[ct] = __builtin_amdgcn_mfma_f32_16x16x32_bf16(kf, qf[c], sa[ct], 0, 0, 0);
      }
    }
    if (last) {
      #pragma unroll
      for (int ct = 0; ct < 4; ++ct)
        #pragma unroll
        for (int j = 0; j < 4; ++j)
          if (ct * 16 + lg * 4 + j > w * 16 + lr) sa[ct][j] = -1e30f;
    }
    float rmax = sa[0][0];
    #pragma unroll
    for (int ct = 0; ct < 4; ++ct)
      #pragma unroll
      for (int j = 0; j < 4; ++j) rmax = fmaxf(rmax, sa[ct][j]);
    rmax = fmaxf(rmax, __shfl_xor(rmax, 16));
    rmax = fmaxf(rmax, __shfl_xor(rmax, 32));
    float mn    = fmaxf(m_run, rmax);
    float alpha = exp2f(m_run - mn);
    m_run = mn;
    #pragma unroll
    for (int ct = 0; ct < 4; ++ct) {
      bf16x4 t;
      #pragma unroll
      for (int j = 0; j < 4; ++j) t[j] = (__bf16)exp2f(sa[ct][j] - mn);
      int b = lr * 128 + ((ct * 32 + lg * 8) ^ swz);
      *reinterpret_cast<bf16x4*>(&p_lds[w][b]) = t;
    }
    float aj[4];
    #pragma unroll
    for (int j = 0; j < 4; ++j) aj[j] = __shfl(alpha, (lane & 48) | (lg * 4 + j));
    #pragma unroll
    for (int j = 0; j < 4; ++j) {
      pl[j] *= aj[j];
      #pragma unroll
      for (int dt = 0; dt < 4; ++dt) po[dt][j] *= aj[j];
    }
    #pragma unroll
    for (int c = 0; c < 2; ++c) {
      int ab = lr * 128 + ((lg * 16 + c * 64) ^ swz);
      bf16x8 pa = *reinterpret_cast<const bf16x8*>(&p_lds[w][ab]);
      pl = __builtin_amdgcn_mfma_f32_16x16x32_bf16(pa, onesf, pl, 0, 0, 0);
      #pragma unroll
      for (int dt = 0; dt < 4; ++dt) {
        int vb_ = (dt * 16 + lr) * 128 + ((lg * 16 + c * 64) ^ swz);
        bf16x8 vb = *reinterpret_cast<const bf16x8*>(&vt_lds[vb_]);
        po[dt] = __builtin_amdgcn_mfma_f32_16x16x32_bf16(pa, vb, po[dt], 0, 0, 0);
      }
    }
    if (!last) {
      __syncthreads();
      write_buf();
      __syncthreads();
    }
  }
  #pragma unroll
  for (int j = 0; j < 4; ++j) {
    float lv  = __shfl(pl[j], lane & 48);
    float inv = 1.0f / lv;
    int row = q0 + w * 16 + lg * 4 + j;
    #pragma unroll
    for (int dt = 0; dt < 4; ++dt)
      Og[base + row * D_DIM + dt * 16 + lr] = po[dt][j] * inv;
  }
}

extern "C" void kernel_launch(void* const* d_in, const int* in_sizes, int n_in,
                              void* d_out, int out_size, void* d_ws, size_t ws_size,
                              hipStream_t stream) {
  const float* V = (const float*)d_in[0];
  const float* Q = (const float*)d_in[1];
  const float* K = (const float*)d_in[2];
  float* O = (float*)d_out;
  const size_t need = (size_t)2 * 32 * 64 * 4096;  // Kb + Vt = 16 MB
  if (ws_size >= need) {
    unsigned char* Kb = (unsigned char*)d_ws;
    unsigned char* Vt = Kb + (size_t)32 * 64 * 4096;
    preprocess_kernel<<<dim3(2048), dim3(256), 0, stream>>>(K, V, Kb, Vt);
    attn_fwd_q64<<<dim3(512), dim3(256), 0, stream>>>(Q, Kb, Vt, O);
  } else {
    attn_fwd_fallback<<<dim3(1024), dim3(256), 0, stream>>>(V, Q, K, O);
  }
}

// Round 21
// 57.940 us; speedup vs baseline: 1.0196x; 1.0196x over previous
//
#include <hip/hip_runtime.h>
#include <hip/hip_bf16.h>

typedef __bf16 bf16x8 __attribute__((ext_vector_type(8)));
typedef __bf16 bf16x4 __attribute__((ext_vector_type(4)));
typedef __bf16 bf16x2 __attribute__((ext_vector_type(2)));
typedef float f32x4 __attribute__((ext_vector_type(4)));
typedef float f32x16 __attribute__((ext_vector_type(16)));

#define S_LEN 2048
#define D_DIM 64
#define NQT   32

// pack two f32 -> u32 of 2 bf16 (compiler fuses to v_cvt_pk_bf16_f32)
static __device__ __forceinline__ unsigned pk2(float a, float b) {
  bf16x2 t; t[0] = (__bf16)a; t[1] = (__bf16)b;
  return __builtin_bit_cast(unsigned, t);
}

// ---------------- preprocess: 32x32-MFMA fragment images (r11-verified) ----------------
__global__ __launch_bounds__(256) void preprocess_kernel(
    const float* __restrict__ Kg, const float* __restrict__ Vg,
    unsigned char* __restrict__ Kb, unsigned char* __restrict__ Vt) {
  __shared__ float buf[2048];   // 8 KB: one 32x64 fp32 tile
  const int tid  = threadIdx.x;
  const int tile = blockIdx.x;          // bh*64 + kt
  const float* kg = Kg + (long)tile * 2048;
  const float* vg = Vg + (long)tile * 2048;
  unsigned char* kb = Kb + (long)tile * 4096;
  unsigned char* vt = Vt + (long)tile * 4096;

  const int l = tid & 63, f = tid >> 6, h = l >> 5;

  {
    const float* kr = kg + (l & 31) * 64 + f * 16 + h * 8;
    float4 a = *reinterpret_cast<const float4*>(kr);
    float4 b = *reinterpret_cast<const float4*>(kr + 4);
    bf16x8 t;
    t[0]=(__bf16)a.x; t[1]=(__bf16)a.y; t[2]=(__bf16)a.z; t[3]=(__bf16)a.w;
    t[4]=(__bf16)b.x; t[5]=(__bf16)b.y; t[6]=(__bf16)b.z; t[7]=(__bf16)b.w;
    *reinterpret_cast<bf16x8*>(kb + tid * 16) = t;
  }
  #pragma unroll
  for (int i = 0; i < 2; ++i) {
    int idx = tid + 256 * i;
    *reinterpret_cast<float4*>(buf + idx * 4) =
        *reinterpret_cast<const float4*>(vg + idx * 4);
  }
  __syncthreads();
  {
    int dt = f >> 1, ks = f & 1;
    int d  = dt * 32 + (l & 31);
    int k0 = ks * 16 + h * 8;
    bf16x8 t;
    #pragma unroll
    for (int j = 0; j < 8; ++j) t[j] = (__bf16)buf[(k0 + j) * 64 + d];
    *reinterpret_cast<bf16x8*>(vt + tid * 16) = t;
  }
}

// ---------------- main: 64 q-rows per wave, balanced pairs, split-K x4 ----------------
// Final configuration (best verified: 58.0 us total, main 52.3, VGPR 128, no
// spill). Block = 256 threads = 4 waves on pair (pi, 31-pi): exactly 66
// tile-iters per block -> perfect balance (2 blocks/CU, no drain). Sub-blocks
// A/B share every K/V fragment load (16 MFMAs per 8 KB). Wave w takes
// kt = w (mod 4), private (m,l,O); 4-way LDS flash-merge per sub-block.
// Structure space characterized r13-r20; this point dominates.
__global__ __launch_bounds__(256, 2) void attn_fwd_q64(
    const float* __restrict__ Qg, const unsigned char* __restrict__ Kb,
    const unsigned char* __restrict__ Vt, float* __restrict__ Og) {
  __shared__ float o_sm[4][32][68];   // 34816 B merge arena (reused A then B)
  __shared__ float m_sm[4][32];
  __shared__ float l_sm[4][32];

  const int tid  = threadIdx.x;
  const int lane = tid & 63;
  const int w    = tid >> 6;     // wave 0..3 (k-residue)
  const int qc   = lane & 31;
  const int h    = lane >> 5;

  // decode: XCD-clustered bh (4 bh per XCD); pair index pi (0..15)
  const int b  = blockIdx.x;            // 0..511
  const int e  = b & 7;
  const int s  = b >> 3;                // 0..63
  const int bh = e + 8 * (s >> 4);      // 4 bh per XCD
  const int pi = s & 15;
  const long base = (long)bh * (S_LEN * D_DIM);

  const unsigned char* kb_bh = Kb + (long)bh * 64 * 4096 + lane * 16;
  const unsigned char* vt_bh = Vt + (long)bh * 64 * 4096 + lane * 16;

  bf16x8 kfr[4], vfr[4];
  auto ldK = [&](int kt) {
    const unsigned char* p = kb_bh + (long)kt * 4096;
    #pragma unroll
    for (int t = 0; t < 4; ++t)
      kfr[t] = *reinterpret_cast<const bf16x8*>(p + t * 1024);
  };
  auto ldV = [&](int kt) {
    const unsigned char* p = vt_bh + (long)kt * 4096;
    #pragma unroll
    for (int t = 0; t < 4; ++t)
      vfr[t] = *reinterpret_cast<const bf16x8*>(p + t * 1024);
  };

  // softmax + PV for one q-sub-block (verified math)
  auto process = [&](f32x16& sa, float& m_run, float& l_run,
                     f32x16& po0, f32x16& po1) {
    float rmax;
    {
      float a0 = fmaxf(fmaxf(sa[0], sa[1]),  fmaxf(sa[2], sa[3]));
      float a1 = fmaxf(fmaxf(sa[4], sa[5]),  fmaxf(sa[6], sa[7]));
      float a2 = fmaxf(fmaxf(sa[8], sa[9]),  fmaxf(sa[10], sa[11]));
      float a3 = fmaxf(fmaxf(sa[12], sa[13]), fmaxf(sa[14], sa[15]));
      rmax = fmaxf(fmaxf(a0, a1), fmaxf(a2, a3));
      rmax = fmaxf(rmax, __shfl_xor(rmax, 32));
    }
    if (__any(rmax > m_run + 8.0f)) {       // defer-max (T13)
      float mn    = fmaxf(m_run, rmax);
      float alpha = exp2f(m_run - mn);
      m_run = mn;
      l_run *= alpha;
      #pragma unroll
      for (int r = 0; r < 16; ++r) {
        float ar = __shfl(alpha, (r & 3) + 8 * (r >> 2) + 4 * h);
        po0[r] *= ar;
        po1[r] *= ar;
      }
    }
    #pragma unroll
    for (int r = 0; r < 16; ++r) sa[r] = exp2f(sa[r] - m_run);
    {
      float s0 = (sa[0] + sa[1]) + (sa[2] + sa[3]);
      float s1 = (sa[4] + sa[5]) + (sa[6] + sa[7]);
      float s2 = (sa[8] + sa[9]) + (sa[10] + sa[11]);
      float s3 = (sa[12] + sa[13]) + (sa[14] + sa[15]);
      float rs = (s0 + s1) + (s2 + s3);
      l_run += rs + __shfl_xor(rs, 32);
    }
    bf16x8 pa0, pa1;
    {
      unsigned k0 = pk2(sa[0], sa[1]),   k1 = pk2(sa[2], sa[3]);
      unsigned k2 = pk2(sa[4], sa[5]),   k3 = pk2(sa[6], sa[7]);
      unsigned k4 = pk2(sa[8], sa[9]),   k5 = pk2(sa[10], sa[11]);
      unsigned k6 = pk2(sa[12], sa[13]), k7 = pk2(sa[14], sa[15]);
      unsigned x02 = h ? k0 : k2, x13 = h ? k1 : k3;
      unsigned x46 = h ? k4 : k6, x57 = h ? k5 : k7;
      unsigned p02 = (unsigned)__shfl_xor((int)x02, 32);
      unsigned p13 = (unsigned)__shfl_xor((int)x13, 32);
      unsigned p46 = (unsigned)__shfl_xor((int)x46, 32);
      unsigned p57 = (unsigned)__shfl_xor((int)x57, 32);
      union { unsigned u[4]; bf16x8 v; } a2, b2;
      a2.u[0] = h ? p02 : k0;  a2.u[1] = h ? p13 : k1;
      a2.u[2] = h ? k2 : p02;  a2.u[3] = h ? k3 : p13;
      b2.u[0] = h ? p46 : k4;  b2.u[1] = h ? p57 : k5;
      b2.u[2] = h ? k6 : p46;  b2.u[3] = h ? k7 : p57;
      pa0 = a2.v;
      pa1 = b2.v;
    }
    __builtin_amdgcn_s_setprio(1);
    po0 = __builtin_amdgcn_mfma_f32_32x32x16_bf16(pa0, vfr[0], po0, 0, 0, 0);
    po0 = __builtin_amdgcn_mfma_f32_32x32x16_bf16(pa1, vfr[1], po0, 0, 0, 0);
    po1 = __builtin_amdgcn_mfma_f32_32x32x16_bf16(pa0, vfr[2], po1, 0, 0, 0);
    po1 = __builtin_amdgcn_mfma_f32_32x32x16_bf16(pa1, vfr[3], po1, 0, 0, 0);
    __builtin_amdgcn_s_setprio(0);
  };

  // merge one 32-row sub-block: write partials -> sync -> 4-way flash-merge
  auto submerge = [&](const f32x16& po0, const f32x16& po1,
                      float m_run, float l_run, int qbase) {
    #pragma unroll
    for (int r = 0; r < 16; ++r) {
      int crow = (r & 3) + 8 * (r >> 2) + 4 * h;
      o_sm[w][crow][qc]      = po0[r];
      o_sm[w][crow][qc + 32] = po1[r];
    }
    if (h == 0) { m_sm[w][qc] = m_run; l_sm[w][qc] = l_run; }
    __syncthreads();
    {
      const int q  = tid >> 3;          // 0..31
      const int d0 = (tid & 7) * 8;     // 0,8,..56
      float m0 = m_sm[0][q], m1 = m_sm[1][q];
      float m2 = m_sm[2][q], m3 = m_sm[3][q];
      float M  = fmaxf(fmaxf(m0, m1), fmaxf(m2, m3));
      float a0 = exp2f(m0 - M), a1 = exp2f(m1 - M);
      float a2 = exp2f(m2 - M), a3 = exp2f(m3 - M);
      float inv = 1.0f / (a0 * l_sm[0][q] + a1 * l_sm[1][q]
                        + a2 * l_sm[2][q] + a3 * l_sm[3][q]);
      float* og = Og + base + (long)(qbase + q) * D_DIM + d0;
      #pragma unroll
      for (int half = 0; half < 2; ++half) {
        float4 x0 = *reinterpret_cast<const float4*>(&o_sm[0][q][d0 + 4 * half]);
        float4 x1 = *reinterpret_cast<const float4*>(&o_sm[1][q][d0 + 4 * half]);
        float4 x2 = *reinterpret_cast<const float4*>(&o_sm[2][q][d0 + 4 * half]);
        float4 x3 = *reinterpret_cast<const float4*>(&o_sm[3][q][d0 + 4 * half]);
        float4 o;
        o.x = (a0 * x0.x + a1 * x1.x + a2 * x2.x + a3 * x3.x) * inv;
        o.y = (a0 * x0.y + a1 * x1.y + a2 * x2.y + a3 * x3.y) * inv;
        o.z = (a0 * x0.z + a1 * x1.z + a2 * x2.z + a3 * x3.z) * inv;
        o.w = (a0 * x0.w + a1 * x1.w + a2 * x2.w + a3 * x3.w) * inv;
        *reinterpret_cast<float4*>(og + 4 * half) = o;
      }
    }
  };

  for (int phase = 0; phase < 2; ++phase) {
    const int g  = phase ? pi : (31 - pi);   // 64-row group
    const int q0 = g * 64;
    const int NT = 2 * g + 2;                // 32-wide k-tiles

    // Q fragments for sub-blocks A and B, prescaled by 1/8 * log2(e)
    bf16x8 qfA[4], qfB[4];
    {
      const float qsc = 0.125f * 1.44269504f;
      const float* qpA = Qg + base + (long)(q0 + qc) * D_DIM + h * 8;
      const float* qpB = qpA + 32 * D_DIM;
      #pragma unroll
      for (int t = 0; t < 4; ++t) {
        float4 f0 = *reinterpret_cast<const float4*>(qpA + t * 16);
        float4 f1 = *reinterpret_cast<const float4*>(qpA + t * 16 + 4);
        bf16x8 q;
        q[0]=(__bf16)(f0.x*qsc); q[1]=(__bf16)(f0.y*qsc);
        q[2]=(__bf16)(f0.z*qsc); q[3]=(__bf16)(f0.w*qsc);
        q[4]=(__bf16)(f1.x*qsc); q[5]=(__bf16)(f1.y*qsc);
        q[6]=(__bf16)(f1.z*qsc); q[7]=(__bf16)(f1.w*qsc);
        qfA[t] = q;
        f0 = *reinterpret_cast<const float4*>(qpB + t * 16);
        f1 = *reinterpret_cast<const float4*>(qpB + t * 16 + 4);
        q[0]=(__bf16)(f0.x*qsc); q[1]=(__bf16)(f0.y*qsc);
        q[2]=(__bf16)(f0.z*qsc); q[3]=(__bf16)(f0.w*qsc);
        q[4]=(__bf16)(f1.x*qsc); q[5]=(__bf16)(f1.y*qsc);
        q[6]=(__bf16)(f1.z*qsc); q[7]=(__bf16)(f1.w*qsc);
        qfB[t] = q;
      }
    }

    f32x16 poA0, poA1, poB0, poB1;
    #pragma unroll
    for (int r = 0; r < 16; ++r) { poA0[r]=0.f; poA1[r]=0.f; poB0[r]=0.f; poB1[r]=0.f; }
    float mA = -1e30f, lA = 0.f, mB = -1e30f, lB = 0.f;

    ldK(w);   // kt = w always exists in the 64-tile bh buffer
    ldV(w);

    for (int kt = w; kt < NT; kt += 4) {
      const bool more = (kt + 4 < NT);
      const bool doA  = (kt != NT - 1);   // tile NT-1 is fully past A's rows

      // S^T via mfma(K, Q) for both sub-blocks (shared kfr)
      f32x16 saA, saB;
      __builtin_amdgcn_s_setprio(1);
      if (doA) {
        #pragma unroll
        for (int r = 0; r < 16; ++r) saA[r] = 0.f;
        #pragma unroll
        for (int t = 0; t < 4; ++t)
          saA = __builtin_amdgcn_mfma_f32_32x32x16_bf16(kfr[t], qfA[t], saA, 0, 0, 0);
      }
      #pragma unroll
      for (int r = 0; r < 16; ++r) saB[r] = 0.f;
      #pragma unroll
      for (int t = 0; t < 4; ++t)
        saB = __builtin_amdgcn_mfma_f32_32x32x16_bf16(kfr[t], qfB[t], saB, 0, 0, 0);
      __builtin_amdgcn_s_setprio(0);

      if (more) ldK(kt + 4);   // prefetch next K (kfr free after both QKs)

      // causal diag masks: A at kt==NT-2, B at kt==NT-1; both reduce to crow>qc
      if (kt == NT - 2) {
        #pragma unroll
        for (int r = 0; r < 16; ++r)
          if (((r & 3) + 8 * (r >> 2) + 4 * h) > qc) saA[r] = -1e30f;
      }
      if (kt == NT - 1) {
        #pragma unroll
        for (int r = 0; r < 16; ++r)
          if (((r & 3) + 8 * (r >> 2) + 4 * h) > qc) saB[r] = -1e30f;
      }

      if (doA) process(saA, mA, lA, poA0, poA1);
      process(saB, mB, lB, poB0, poB1);

      if (more) ldV(kt + 4);   // prefetch next V
    }

    if (phase) __syncthreads();          // prior merge readers done
    submerge(poA0, poA1, mA, lA, q0);
    __syncthreads();                     // merge-A reads done before B writes
    submerge(poB0, poB1, mB, lB, q0 + 32);
  }
}

// ---------------- fallback (round-5 kernel) if ws too small ----------------
__global__ __launch_bounds__(256) void attn_fwd_fallback(
    const float* __restrict__ Vg, const float* __restrict__ Qg,
    const float* __restrict__ Kg, float* __restrict__ Og) {
  __shared__ __align__(16) unsigned char k_lds[64 * 128];
  __shared__ __align__(16) unsigned char vt_lds[64 * 128];
  __shared__ __align__(16) unsigned char p_lds[4][16 * 128];

  const int tid  = threadIdx.x;
  const int lane = tid & 63;
  const int w    = tid >> 6;
  const int lr   = lane & 15;
  const int lg   = lane >> 4;
  const int swz  = (lr & 7) << 4;

  const int lb = blockIdx.x;
  const int e  = lb & 7;
  const int s  = lb >> 3;
  const int bh = e + 8 * (s >> 5);
  const int qs = s & 31;
  const int qt = (qs & 1) ? (NQT - 1 - (qs >> 1)) : (qs >> 1);
  const long base = (long)bh * (S_LEN * D_DIM);
  const int q0 = qt * 64;

  bf16x8 qf[2];
  {
    const float qsc = 0.125f * 1.44269504f;
    const float* qp = Qg + base + (q0 + w * 16 + lr) * D_DIM + lg * 8;
    #pragma unroll
    for (int c = 0; c < 2; ++c) {
      float4 f0 = *reinterpret_cast<const float4*>(qp + c * 32);
      float4 f1 = *reinterpret_cast<const float4*>(qp + c * 32 + 4);
      bf16x8 t;
      t[0]=(__bf16)(f0.x*qsc); t[1]=(__bf16)(f0.y*qsc);
      t[2]=(__bf16)(f0.z*qsc); t[3]=(__bf16)(f0.w*qsc);
      t[4]=(__bf16)(f1.x*qsc); t[5]=(__bf16)(f1.y*qsc);
      t[6]=(__bf16)(f1.z*qsc); t[7]=(__bf16)(f1.w*qsc);
      qf[c] = t;
    }
  }
  bf16x8 onesf;
  #pragma unroll
  for (int j = 0; j < 8; ++j) onesf[j] = (lr == 0) ? (__bf16)1.0f : (__bf16)0.0f;

  f32x4 po[4], pl;
  float m_run = -1e30f;
  #pragma unroll
  for (int j = 0; j < 4; ++j) po[j] = (f32x4){0.f,0.f,0.f,0.f};
  pl = (f32x4){0.f,0.f,0.f,0.f};

  float4 kreg[4];
  float  vreg[16];
  const int d_ = lane;
  const int kb = w;

  auto load_regs = [&](int kt) {
    const float* kg = Kg + base + kt * (64 * D_DIM);
    #pragma unroll
    for (int i = 0; i < 4; ++i) {
      int idx = tid + 256 * i;
      int r = idx >> 4, f4 = idx & 15;
      kreg[i] = *reinterpret_cast<const float4*>(kg + r * 64 + f4 * 4);
    }
    const float* vg = Vg + base + kt * (64 * D_DIM);
    #pragma unroll
    for (int j = 0; j < 8; ++j) {
      vreg[j]     = vg[(kb * 8 + j) * 64 + d_];
      vreg[8 + j] = vg[((kb + 4) * 8 + j) * 64 + d_];
    }
  };
  auto write_buf = [&]() {
    #pragma unroll
    for (int i = 0; i < 4; ++i) {
      int idx = tid + 256 * i;
      int r = idx >> 4, f4 = idx & 15;
      bf16x4 t;
      t[0]=(__bf16)kreg[i].x; t[1]=(__bf16)kreg[i].y;
      t[2]=(__bf16)kreg[i].z; t[3]=(__bf16)kreg[i].w;
      int b = r * 128 + ((f4 * 8) ^ ((r & 7) << 4));
      *reinterpret_cast<bf16x4*>(&k_lds[b]) = t;
    }
    bf16x8 t0, t1;
    #pragma unroll
    for (int j = 0; j < 8; ++j) { t0[j] = (__bf16)vreg[j]; t1[j] = (__bf16)vreg[8+j]; }
    int b0 = d_ * 128 + ((kb * 16) ^ ((d_ & 7) << 4));
    int b1 = d_ * 128 + (((kb + 4) * 16) ^ ((d_ & 7) << 4));
    *reinterpret_cast<bf16x8*>(&vt_lds[b0]) = t0;
    *reinterpret_cast<bf16x8*>(&vt_lds[b1]) = t1;
  };

  load_regs(0);
  write_buf();
  __syncthreads();

  for (int kt = 0; kt <= qt; ++kt) {
    const bool last = (kt == qt);
    if (!last) load_regs(kt + 1);

    f32x4 sa[4];
    #pragma unroll
    for (int ct = 0; ct < 4; ++ct) sa[ct] = (f32x4){0.f,0.f,0.f,0.f};
    #pragma unroll
    for (int ct = 0; ct < 4; ++ct) {
      #pragma unroll
      for (int c = 0; c < 2; ++c) {
        int b = (ct * 16 + lr) * 128 + ((lg * 16 + c * 64) ^ swz);
        bf16x8 kf = *reinterpret_cast<const bf16x8*>(&k_lds[b]);
        sa[ct] = __builtin_amdgcn_mfma_f32_16x16x32_bf16(kf, qf[c], sa[ct], 0, 0, 0);
      }
    }
    if (last) {
      #pragma unroll
      for (int ct = 0; ct < 4; ++ct)
        #pragma unroll
        for (int j = 0; j < 4; ++j)
          if (ct * 16 + lg * 4 + j > w * 16 + lr) sa[ct][j] = -1e30f;
    }
    float rmax = sa[0][0];
    #pragma unroll
    for (int ct = 0; ct < 4; ++ct)
      #pragma unroll
      for (int j = 0; j < 4; ++j) rmax = fmaxf(rmax, sa[ct][j]);
    rmax = fmaxf(rmax, __shfl_xor(rmax, 16));
    rmax = fmaxf(rmax, __shfl_xor(rmax, 32));
    float mn    = fmaxf(m_run, rmax);
    float alpha = exp2f(m_run - mn);
    m_run = mn;
    #pragma unroll
    for (int ct = 0; ct < 4; ++ct) {
      bf16x4 t;
      #pragma unroll
      for (int j = 0; j < 4; ++j) t[j] = (__bf16)exp2f(sa[ct][j] - mn);
      int b = lr * 128 + ((ct * 32 + lg * 8) ^ swz);
      *reinterpret_cast<bf16x4*>(&p_lds[w][b]) = t;
    }
    float aj[4];
    #pragma unroll
    for (int j = 0; j < 4; ++j) aj[j] = __shfl(alpha, (lane & 48) | (lg * 4 + j));
    #pragma unroll
    for (int j = 0; j < 4; ++j) {
      pl[j] *= aj[j];
      #pragma unroll
      for (int dt = 0; dt < 4; ++dt) po[dt][j] *= aj[j];
    }
    #pragma unroll
    for (int c = 0; c < 2; ++c) {
      int ab = lr * 128 + ((lg * 16 + c * 64) ^ swz);
      bf16x8 pa = *reinterpret_cast<const bf16x8*>(&p_lds[w][ab]);
      pl = __builtin_amdgcn_mfma_f32_16x16x32_bf16(pa, onesf, pl, 0, 0, 0);
      #pragma unroll
      for (int dt = 0; dt < 4; ++dt) {
        int vb_ = (dt * 16 + lr) * 128 + ((lg * 16 + c * 64) ^ swz);
        bf16x8 vb = *reinterpret_cast<const bf16x8*>(&vt_lds[vb_]);
        po[dt] = __builtin_amdgcn_mfma_f32_16x16x32_bf16(pa, vb, po[dt], 0, 0, 0);
      }
    }
    if (!last) {
      __syncthreads();
      write_buf();
      __syncthreads();
    }
  }
  #pragma unroll
  for (int j = 0; j < 4; ++j) {
    float lv  = __shfl(pl[j], lane & 48);
    float inv = 1.0f / lv;
    int row = q0 + w * 16 + lg * 4 + j;
    #pragma unroll
    for (int dt = 0; dt < 4; ++dt)
      Og[base + row * D_DIM + dt * 16 + lr] = po[dt][j] * inv;
  }
}

extern "C" void kernel_launch(void* const* d_in, const int* in_sizes, int n_in,
                              void* d_out, int out_size, void* d_ws, size_t ws_size,
                              hipStream_t stream) {
  const float* V = (const float*)d_in[0];
  const float* Q = (const float*)d_in[1];
  const float* K = (const float*)d_in[2];
  float* O = (float*)d_out;
  const size_t need = (size_t)2 * 32 * 64 * 4096;  // Kb + Vt = 16 MB
  if (ws_size >= need) {
    unsigned char* Kb = (unsigned char*)d_ws;
    unsigned char* Vt = Kb + (size_t)32 * 64 * 4096;
    preprocess_kernel<<<dim3(2048), dim3(256), 0, stream>>>(K, V, Kb, Vt);
    attn_fwd_q64<<<dim3(512), dim3(256), 0, stream>>>(Q, Kb, Vt, O);
  } else {
    attn_fwd_fallback<<<dim3(1024), dim3(256), 0, stream>>>(V, Q, K, O);
  }
}